// Round 3
// baseline (398.211 us; speedup 1.0000x reference)
//
#include <hip/hip_runtime.h>
#include <math.h>

// Problem dims
// B=4, N_IN=128, NODE=32, L=256, N_HID=D_IN=64, D_STATE=128, DT_RANK=4, N_OUT=128
// R = B*NODE = 128 rows, each row is an independent sequence of length 256.

__device__ __forceinline__ float silu_f(float v) { return v / (1.f + __expf(-v)); }
__device__ __forceinline__ float softplus_f(float v) { return v > 20.f ? v : log1pf(__expf(v)); }

// ---------------------------------------------------------------------------
// K1: X = in @ w_in.T + b_in ; XZ = X @ in_proj_w.T -> XM (first 64), Z (last 64)
// grid 512 = 128 rows x 4 t-tiles(64), block 256
// ---------------------------------------------------------------------------
__global__ __launch_bounds__(256) void k1_proj(
    const float* __restrict__ inp, const float* __restrict__ w_in,
    const float* __restrict__ b_in, const float* __restrict__ ipw,
    float* __restrict__ XM, float* __restrict__ Zb)
{
  __shared__ float sIN[128*64];   // [k=i][t], k-major
  const int bid = blockIdx.x;
  const int r = bid >> 2, tb = bid & 3;
  const int b = r >> 5, node = r & 31;
  const int t0 = tb * 64;
  const int tid = threadIdx.x;

  for (int e = tid; e < 128*64; e += 256) {
    int i = e >> 6, t = e & 63;
    sIN[e] = inp[((b*128 + i)*32 + node)*256 + t0 + t];
  }
  __syncthreads();

  // X phase: out tile 64t x 64h, thread = 4t x 4h
  const int tg = tid >> 4, hg = tid & 15;
  const int tl0 = tg * 4, h0 = hg * 4;
  float acc[4][4];
  #pragma unroll
  for (int ti = 0; ti < 4; ti++)
    #pragma unroll
    for (int j = 0; j < 4; j++) acc[ti][j] = b_in[h0 + j];

  for (int k4 = 0; k4 < 32; k4++) {
    float4 wv[4];
    #pragma unroll
    for (int j = 0; j < 4; j++)
      wv[j] = *(const float4*)&w_in[(h0 + j)*128 + k4*4];
    #pragma unroll
    for (int kk = 0; kk < 4; kk++) {
      float4 x4 = *(const float4*)&sIN[(k4*4 + kk)*64 + tl0];
      #pragma unroll
      for (int j = 0; j < 4; j++) {
        float w = kk==0 ? wv[j].x : kk==1 ? wv[j].y : kk==2 ? wv[j].z : wv[j].w;
        acc[0][j] = fmaf(x4.x, w, acc[0][j]);
        acc[1][j] = fmaf(x4.y, w, acc[1][j]);
        acc[2][j] = fmaf(x4.z, w, acc[2][j]);
        acc[3][j] = fmaf(x4.w, w, acc[3][j]);
      }
    }
  }
  __syncthreads();
  // stash X into sXT [64][68] (reuse sIN region)
  float* sXT = sIN;
  #pragma unroll
  for (int ti = 0; ti < 4; ti++) {
    float4 v = make_float4(acc[ti][0], acc[ti][1], acc[ti][2], acc[ti][3]);
    *(float4*)&sXT[(tl0 + ti)*68 + h0] = v;
  }
  __syncthreads();

  // XZ phase: out tile 64t x 128c, thread = 8t x 4c
  const int tg2 = tid >> 5, cg = tid & 31;
  const int tl2 = tg2 * 8, c0 = cg * 4;
  float a2[8][4];
  #pragma unroll
  for (int ti = 0; ti < 8; ti++)
    #pragma unroll
    for (int j = 0; j < 4; j++) a2[ti][j] = 0.f;

  for (int k4 = 0; k4 < 16; k4++) {
    float4 wv[4];
    #pragma unroll
    for (int j = 0; j < 4; j++)
      wv[j] = *(const float4*)&ipw[(c0 + j)*64 + k4*4];
    #pragma unroll
    for (int ti = 0; ti < 8; ti++) {
      float4 x4 = *(const float4*)&sXT[(tl2 + ti)*68 + k4*4];
      #pragma unroll
      for (int kk = 0; kk < 4; kk++) {
        float xk = kk==0 ? x4.x : kk==1 ? x4.y : kk==2 ? x4.z : x4.w;
        #pragma unroll
        for (int j = 0; j < 4; j++) {
          float w = kk==0 ? wv[j].x : kk==1 ? wv[j].y : kk==2 ? wv[j].z : wv[j].w;
          a2[ti][j] = fmaf(xk, w, a2[ti][j]);
        }
      }
    }
  }

  float* dst = (c0 < 64) ? XM : Zb;
  const int cc = (c0 < 64) ? c0 : c0 - 64;
  #pragma unroll
  for (int ti = 0; ti < 8; ti++) {
    int t = t0 + tl2 + ti;
    float4 v = make_float4(a2[ti][0], a2[ti][1], a2[ti][2], a2[ti][3]);
    *(float4*)&dst[(r*256 + t)*64 + cc] = v;
  }
}

// ---------------------------------------------------------------------------
// K2: conv+silu -> XC ; dbc = xc @ x_proj_w.T -> (dt | B | C) ; delta = softplus(dt@dtw.T+b)
// grid 512 = 128 rows x 4 t-tiles(64), block 256
// ---------------------------------------------------------------------------
__global__ __launch_bounds__(256) void k2_conv_xproj(
    const float* __restrict__ XM, const float* __restrict__ convw,
    const float* __restrict__ convb, const float* __restrict__ xpw,
    const float* __restrict__ dtw, const float* __restrict__ dtb,
    float* __restrict__ XC, float* __restrict__ DELTA,
    float* __restrict__ BM, float* __restrict__ CM)
{
  __shared__ float sXM[65*64];     // [tt in -1..63][d]
  __shared__ float sXC[64*68];     // [t][d] padded
  __shared__ float sDT[64*4];
  const int bid = blockIdx.x;
  const int r = bid >> 2, tb = bid & 3;
  const int t0 = tb * 64;
  const int tid = threadIdx.x;

  for (int e = tid; e < 65*64; e += 256) {
    int tt = e >> 6, d = e & 63;
    int tg = t0 - 1 + tt;
    sXM[e] = (tg < 0) ? 0.f : XM[(r*256 + tg)*64 + d];
  }
  __syncthreads();

  for (int e = tid; e < 64*64; e += 256) {
    int t = e >> 6, d = e & 63;
    float c0 = convw[d*2], c1 = convw[d*2 + 1];
    float pre = fmaf(sXM[t*64 + d], c0, fmaf(sXM[(t+1)*64 + d], c1, convb[d]));
    float v = silu_f(pre);
    sXC[t*68 + d] = v;
    XC[(r*256 + t0 + t)*64 + d] = v;
  }
  __syncthreads();

  const int tg = tid >> 4, jg = tid & 15;
  const int tl0 = tg * 4;
  for (int pass = 0; pass < 5; pass++) {
    float acc[4][4];
    #pragma unroll
    for (int ti = 0; ti < 4; ti++)
      #pragma unroll
      for (int jj = 0; jj < 4; jj++) acc[ti][jj] = 0.f;

    for (int k4 = 0; k4 < 16; k4++) {
      float4 wv[4];
      #pragma unroll
      for (int jj = 0; jj < 4; jj++) {
        int j = pass*64 + jj*16 + jg;
        if (j > 259) j = 259;   // clamp for OOB-safe read (result discarded)
        wv[jj] = *(const float4*)&xpw[j*64 + k4*4];
      }
      #pragma unroll
      for (int ti = 0; ti < 4; ti++) {
        float4 x4 = *(const float4*)&sXC[(tl0 + ti)*68 + k4*4];
        #pragma unroll
        for (int kk = 0; kk < 4; kk++) {
          float xk = kk==0 ? x4.x : kk==1 ? x4.y : kk==2 ? x4.z : x4.w;
          #pragma unroll
          for (int jj = 0; jj < 4; jj++) {
            float w = kk==0 ? wv[jj].x : kk==1 ? wv[jj].y : kk==2 ? wv[jj].z : wv[jj].w;
            acc[ti][jj] = fmaf(xk, w, acc[ti][jj]);
          }
        }
      }
    }

    #pragma unroll
    for (int ti = 0; ti < 4; ti++) {
      #pragma unroll
      for (int jj = 0; jj < 4; jj++) {
        int j = pass*64 + jj*16 + jg;
        if (j >= 260) continue;
        float v = acc[ti][jj];
        int t = t0 + tl0 + ti;
        if (j < 4)       sDT[(tl0 + ti)*4 + j] = v;
        else if (j < 132) BM[(r*256 + t)*128 + (j - 4)] = v;
        else              CM[(r*256 + t)*128 + (j - 132)] = v;
      }
    }
  }
  __syncthreads();

  for (int e = tid; e < 64*64; e += 256) {
    int t = e >> 6, d = e & 63;
    float4 w4 = *(const float4*)&dtw[d*4];
    float x = dtb[d];
    x = fmaf(sDT[t*4 + 0], w4.x, x);
    x = fmaf(sDT[t*4 + 1], w4.y, x);
    x = fmaf(sDT[t*4 + 2], w4.z, x);
    x = fmaf(sDT[t*4 + 3], w4.w, x);
    DELTA[(r*256 + t0 + t)*64 + d] = softplus_f(x);
  }
}

// ---------------------------------------------------------------------------
// K3: selective scan. grid 256 = 128 rows x 2 s-chunks(64), block 256.
// thread owns 4d x 4s state micro-tile in registers across all 256 timesteps.
// writes partial y per s-chunk: YP[sc][r][t][d]
// ---------------------------------------------------------------------------
__global__ __launch_bounds__(256) void k3_scan(
    const float* __restrict__ DELTA, const float* __restrict__ XC,
    const float* __restrict__ BM, const float* __restrict__ CM,
    const float* __restrict__ alog, float* __restrict__ YP)
{
  __shared__ float sD[8*64], sX[8*64], sB[8*64], sC[8*64];
  const int bid = blockIdx.x;
  const int r = bid & 127, sc = bid >> 7;
  const int tid = threadIdx.x;
  const int dg = tid >> 4, sg = tid & 15;
  const int d0 = dg * 4, s0 = sc*64 + sg*4;

  float a[4][4], h[4][4];
  #pragma unroll
  for (int i = 0; i < 4; i++)
    #pragma unroll
    for (int j = 0; j < 4; j++) {
      a[i][j] = -expf(alog[(d0 + i)*128 + s0 + j]);
      h[i][j] = 0.f;
    }

  for (int tb = 0; tb < 32; tb++) {
    for (int e = tid; e < 512; e += 256) {
      int tt = e >> 6, q = e & 63;
      int t = tb*8 + tt;
      sD[e] = DELTA[(r*256 + t)*64 + q];
      sX[e] = XC[(r*256 + t)*64 + q];
      sB[e] = BM[(r*256 + t)*128 + sc*64 + q];
      sC[e] = CM[(r*256 + t)*128 + sc*64 + q];
    }
    __syncthreads();

    #pragma unroll
    for (int tt = 0; tt < 8; tt++) {
      float4 dl4 = *(const float4*)&sD[tt*64 + d0];
      float4 xc4 = *(const float4*)&sX[tt*64 + d0];
      float4 B4  = *(const float4*)&sB[tt*64 + sg*4];
      float4 C4  = *(const float4*)&sC[tt*64 + sg*4];
      float dl[4] = {dl4.x, dl4.y, dl4.z, dl4.w};
      float xc[4] = {xc4.x, xc4.y, xc4.z, xc4.w};
      float Bv[4] = {B4.x, B4.y, B4.z, B4.w};
      float Cv[4] = {C4.x, C4.y, C4.z, C4.w};
      float y[4];
      #pragma unroll
      for (int i = 0; i < 4; i++) {
        float u = dl[i] * xc[i];
        float yp = 0.f;
        #pragma unroll
        for (int j = 0; j < 4; j++) {
          float dA = __expf(dl[i] * a[i][j]);
          h[i][j] = fmaf(dA, h[i][j], u * Bv[j]);
          yp = fmaf(h[i][j], Cv[j], yp);
        }
        y[i] = yp;
      }
      #pragma unroll
      for (int i = 0; i < 4; i++) {
        float yp = y[i];
        yp += __shfl_xor(yp, 1);
        yp += __shfl_xor(yp, 2);
        yp += __shfl_xor(yp, 4);
        yp += __shfl_xor(yp, 8);
        y[i] = yp;
      }
      if (sg == 0) {
        int t = tb*8 + tt;
        float4 v = make_float4(y[0], y[1], y[2], y[3]);
        *(float4*)&YP[((sc*128 + r)*256 + t)*64 + d0] = v;
      }
    }
    __syncthreads();
  }
}

// ---------------------------------------------------------------------------
// K4: y = yp0+yp1 ; y2 = y + xc*D ; y3 = y2*silu(z) ; u = silu(y3@opw.T) ;
//     v = u@wout.T + bout -> d_out (final layout, pre-LN) + per-block stats
// grid 512 = 128 rows x 4 t-tiles(64), block 256
// ---------------------------------------------------------------------------
__global__ __launch_bounds__(256) void k4_post(
    const float* __restrict__ YP, const float* __restrict__ XC,
    const float* __restrict__ Zb, const float* __restrict__ Dp,
    const float* __restrict__ opw, const float* __restrict__ wout,
    const float* __restrict__ bout, float* __restrict__ out,
    float* __restrict__ PSTAT)
{
  __shared__ float sY[64*68];
  __shared__ float sU[64*68];
  __shared__ float sRs[256], sRq[256];
  const int bid = blockIdx.x;
  const int r = bid >> 2, tb = bid & 3;
  const int b = r >> 5, node = r & 31;
  const int t0 = tb * 64;
  const int tid = threadIdx.x;

  for (int e = tid; e < 64*64; e += 256) {
    int t = e >> 6, d = e & 63;
    int idx = (r*256 + t0 + t)*64 + d;
    float y = YP[idx] + YP[2097152 + idx];
    float y2 = fmaf(XC[idx], Dp[d], y);
    float y3 = y2 * silu_f(Zb[idx]);
    sY[t*68 + d] = y3;
  }
  __syncthreads();

  const int tg = tid >> 4, eg = tid & 15;
  const int tl0 = tg * 4, e0 = eg * 4;
  {
    float acc[4][4];
    #pragma unroll
    for (int ti = 0; ti < 4; ti++)
      #pragma unroll
      for (int j = 0; j < 4; j++) acc[ti][j] = 0.f;
    for (int k4 = 0; k4 < 16; k4++) {
      float4 wv[4];
      #pragma unroll
      for (int j = 0; j < 4; j++)
        wv[j] = *(const float4*)&opw[(e0 + j)*64 + k4*4];
      #pragma unroll
      for (int ti = 0; ti < 4; ti++) {
        float4 x4 = *(const float4*)&sY[(tl0 + ti)*68 + k4*4];
        #pragma unroll
        for (int kk = 0; kk < 4; kk++) {
          float xk = kk==0 ? x4.x : kk==1 ? x4.y : kk==2 ? x4.z : x4.w;
          #pragma unroll
          for (int j = 0; j < 4; j++) {
            float w = kk==0 ? wv[j].x : kk==1 ? wv[j].y : kk==2 ? wv[j].z : wv[j].w;
            acc[ti][j] = fmaf(xk, w, acc[ti][j]);
          }
        }
      }
    }
    __syncthreads();   // done reading sY (sU is separate, but keep ordering clean)
    #pragma unroll
    for (int ti = 0; ti < 4; ti++) {
      float4 v = make_float4(silu_f(acc[ti][0]), silu_f(acc[ti][1]),
                             silu_f(acc[ti][2]), silu_f(acc[ti][3]));
      *(float4*)&sU[(tl0 + ti)*68 + e0] = v;
    }
  }
  __syncthreads();

  const int og = tid & 15, o0 = og * 8;
  float acc2[4][8];
  #pragma unroll
  for (int ti = 0; ti < 4; ti++)
    #pragma unroll
    for (int oj = 0; oj < 8; oj++) acc2[ti][oj] = bout[o0 + oj];

  for (int k4 = 0; k4 < 16; k4++) {
    float4 wv[8];
    #pragma unroll
    for (int oj = 0; oj < 8; oj++)
      wv[oj] = *(const float4*)&wout[(o0 + oj)*64 + k4*4];
    #pragma unroll
    for (int ti = 0; ti < 4; ti++) {
      float4 x4 = *(const float4*)&sU[(tl0 + ti)*68 + k4*4];
      #pragma unroll
      for (int kk = 0; kk < 4; kk++) {
        float xk = kk==0 ? x4.x : kk==1 ? x4.y : kk==2 ? x4.z : x4.w;
        #pragma unroll
        for (int oj = 0; oj < 8; oj++) {
          float w = kk==0 ? wv[oj].x : kk==1 ? wv[oj].y : kk==2 ? wv[oj].z : wv[oj].w;
          acc2[ti][oj] = fmaf(xk, w, acc2[ti][oj]);
        }
      }
    }
  }

  float s = 0.f, q = 0.f;
  #pragma unroll
  for (int ti = 0; ti < 4; ti++)
    #pragma unroll
    for (int oj = 0; oj < 8; oj++) {
      float v = acc2[ti][oj];
      s += v;
      q = fmaf(v, v, q);
    }
  #pragma unroll
  for (int oj = 0; oj < 8; oj++) {
    int o = o0 + oj;
    float4 v = make_float4(acc2[0][oj], acc2[1][oj], acc2[2][oj], acc2[3][oj]);
    *(float4*)&out[((b*128 + o)*32 + node)*256 + t0 + tl0] = v;
  }

  sRs[tid] = s; sRq[tid] = q;
  __syncthreads();
  for (int st = 128; st > 0; st >>= 1) {
    if (tid < st) { sRs[tid] += sRs[tid + st]; sRq[tid] += sRq[tid + st]; }
    __syncthreads();
  }
  if (tid == 0) { PSTAT[bid*2] = sRs[0]; PSTAT[bid*2 + 1] = sRq[0]; }
}

// ---------------------------------------------------------------------------
// K5: LayerNorm in place on d_out. grid 1024 = 128 rows x 8 t-tiles(32), block 256
// ---------------------------------------------------------------------------
__global__ __launch_bounds__(256) void k5_ln(
    const float* __restrict__ PSTAT, const float* __restrict__ lnw,
    const float* __restrict__ lnb, float* __restrict__ out)
{
  __shared__ float sLW[32*129], sLB[32*129];
  const int bid = blockIdx.x;
  const int r = bid >> 3, tb = bid & 7;
  const int b = r >> 5, node = r & 31;
  const int t0 = tb * 32;
  const int tid = threadIdx.x;

  float s = 0.f, q = 0.f;
  #pragma unroll
  for (int p = 0; p < 4; p++) {
    s += PSTAT[(r*4 + p)*2];
    q += PSTAT[(r*4 + p)*2 + 1];
  }
  const float mu = s * (1.f / 32768.f);
  const float var = q * (1.f / 32768.f) - mu * mu;
  const float rstd = rsqrtf(var + 1e-5f);

  for (int e = tid; e < 32*128; e += 256) {
    int t = e >> 7, o = e & 127;
    sLW[t*129 + o] = lnw[(t0 + t)*128 + o];
    sLB[t*129 + o] = lnb[(t0 + t)*128 + o];
  }
  __syncthreads();

  for (int n = 0; n < 16; n++) {
    int t = tid & 31;
    int o = (tid >> 5) + n*8;
    int idx = ((b*128 + o)*32 + node)*256 + t0 + t;
    float v = out[idx];
    out[idx] = fmaf((v - mu) * rstd, sLW[t*129 + o], sLB[t*129 + o]);
  }
}

// ---------------------------------------------------------------------------
extern "C" void kernel_launch(void* const* d_in, const int* in_sizes, int n_in,
                              void* d_out, int out_size, void* d_ws, size_t ws_size,
                              hipStream_t stream)
{
  (void)in_sizes; (void)n_in; (void)out_size; (void)ws_size;
  const float* inp   = (const float*)d_in[0];
  const float* w_in  = (const float*)d_in[1];
  const float* b_in  = (const float*)d_in[2];
  const float* ipw   = (const float*)d_in[3];
  const float* convw = (const float*)d_in[4];
  const float* convb = (const float*)d_in[5];
  const float* xpw   = (const float*)d_in[6];
  const float* dtw   = (const float*)d_in[7];
  const float* dtb   = (const float*)d_in[8];
  const float* alog  = (const float*)d_in[9];
  const float* Dp    = (const float*)d_in[10];
  const float* opw   = (const float*)d_in[11];
  const float* wout  = (const float*)d_in[12];
  const float* bout  = (const float*)d_in[13];
  const float* lnw   = (const float*)d_in[14];
  const float* lnb   = (const float*)d_in[15];

  float* ws = (float*)d_ws;
  float* XM    = ws + 0;
  float* Zb    = ws + 2097152;
  float* XC    = ws + 4194304;
  float* DELTA = ws + 6291456;
  float* BM    = ws + 8388608;
  float* CM    = ws + 12582912;
  float* YP    = ws + 16777216;   // 2 x 128 x 256 x 64
  float* PSTAT = ws + 20971520;   // 512 x 2
  float* out   = (float*)d_out;

  k1_proj<<<dim3(512), dim3(256), 0, stream>>>(inp, w_in, b_in, ipw, XM, Zb);
  k2_conv_xproj<<<dim3(512), dim3(256), 0, stream>>>(XM, convw, convb, xpw, dtw, dtb,
                                                     XC, DELTA, BM, CM);
  k3_scan<<<dim3(256), dim3(256), 0, stream>>>(DELTA, XC, BM, CM, alog, YP);
  k4_post<<<dim3(512), dim3(256), 0, stream>>>(YP, XC, Zb, Dp, opw, wout, bout, out, PSTAT);
  k5_ln<<<dim3(1024), dim3(256), 0, stream>>>(PSTAT, lnw, lnb, out);
}

// Round 4
// 226.684 us; speedup vs baseline: 1.7567x; 1.7567x over previous
//
#include <hip/hip_runtime.h>
#include <math.h>

// Problem dims
// B=4, N_IN=128, NODE=32, L=256, N_HID=D_IN=64, D_STATE=128, DT_RANK=4, N_OUT=128
// R = B*NODE = 128 rows, each row independent; L sequential only in the scan (k3).
//
// R3 change: all weight-consuming GEMMs (k1, k2, k4) now stage weight tiles in
// LDS via coalesced cooperative loads; inner loops read weights as wave
// broadcasts and x-tiles at stride-4 (both conflict-free). Was: per-lane
// splintered global loads -> k2 at 165us, VALUBusy 1.6%, occupancy 0.75%.

__device__ __forceinline__ float silu_f(float v) { return v / (1.f + __expf(-v)); }
__device__ __forceinline__ float softplus_f(float v) { return v > 20.f ? v : log1pf(__expf(v)); }

// ---------------------------------------------------------------------------
// K1: X = in @ w_in.T + b_in ; XZ = X @ in_proj_w.T -> XM (first 64), Z (last 64)
// grid 512 = 128 rows x 4 t-tiles(64), block 256
// thread map: tg=tid&15 -> 4 t-rows, vg=tid>>4 -> 4 out-cols
// ---------------------------------------------------------------------------
__global__ __launch_bounds__(256) void k1_proj(
    const float* __restrict__ inp, const float* __restrict__ w_in,
    const float* __restrict__ b_in, const float* __restrict__ ipw,
    float* __restrict__ XM, float* __restrict__ Zb)
{
  __shared__ float sIN[128*64];   // [i=128][t=64]
  __shared__ float sW[64*68];     // staged weight tile [row][k], stride 68
  __shared__ float sXT[64*68];    // X transposed [h][t], stride 68
  const int bid = blockIdx.x;
  const int r = bid >> 2, tb = bid & 3;
  const int b = r >> 5, node = r & 31;
  const int t0 = tb * 64;
  const int tid = threadIdx.x;
  const int tg = tid & 15, vg = tid >> 4;
  const int tl0 = tg * 4, v0 = vg * 4;

  for (int e = tid; e < 128*64; e += 256) {
    int i = e >> 6, t = e & 63;
    sIN[e] = inp[((b*128 + i)*32 + node)*256 + t0 + t];
  }

  // Phase A: X[t][h] = b_in[h] + sum_i in[i][t] * w_in[h][i]   (K=128, 2 chunks)
  float acc[4][4];
  #pragma unroll
  for (int ti = 0; ti < 4; ti++)
    #pragma unroll
    for (int j = 0; j < 4; j++) acc[ti][j] = b_in[v0 + j];

  for (int kc = 0; kc < 2; kc++) {
    __syncthreads();   // sIN ready (kc=0) / sW read-done (kc=1)
    for (int e = tid; e < 64*16; e += 256) {
      int row = e >> 4, c4 = e & 15;
      *(float4*)&sW[row*68 + c4*4] = *(const float4*)&w_in[row*128 + kc*64 + c4*4];
    }
    __syncthreads();
    for (int k4 = 0; k4 < 16; k4++) {
      float4 wv[4];
      #pragma unroll
      for (int j = 0; j < 4; j++)
        wv[j] = *(const float4*)&sW[(v0 + j)*68 + k4*4];
      #pragma unroll
      for (int kk = 0; kk < 4; kk++) {
        float4 x4 = *(const float4*)&sIN[(kc*64 + k4*4 + kk)*64 + tl0];
        #pragma unroll
        for (int j = 0; j < 4; j++) {
          float w = kk==0 ? wv[j].x : kk==1 ? wv[j].y : kk==2 ? wv[j].z : wv[j].w;
          acc[0][j] = fmaf(x4.x, w, acc[0][j]);
          acc[1][j] = fmaf(x4.y, w, acc[1][j]);
          acc[2][j] = fmaf(x4.z, w, acc[2][j]);
          acc[3][j] = fmaf(x4.w, w, acc[3][j]);
        }
      }
    }
  }
  // stash X^T into sXT[h][t]
  #pragma unroll
  for (int j = 0; j < 4; j++)
    *(float4*)&sXT[(v0 + j)*68 + tl0] =
        make_float4(acc[0][j], acc[1][j], acc[2][j], acc[3][j]);

  // Phase B: XZ[t][c] = sum_h X[h][t] * ipw[c][h]   (c: 2 passes of 64)
  for (int pass = 0; pass < 2; pass++) {
    __syncthreads();   // sXT visible (pass0) / sW read-done
    for (int e = tid; e < 64*16; e += 256) {
      int row = e >> 4, c4 = e & 15;
      *(float4*)&sW[row*68 + c4*4] = *(const float4*)&ipw[(pass*64 + row)*64 + c4*4];
    }
    __syncthreads();

    float a2[4][4];
    #pragma unroll
    for (int ti = 0; ti < 4; ti++)
      #pragma unroll
      for (int j = 0; j < 4; j++) a2[ti][j] = 0.f;

    for (int k4 = 0; k4 < 16; k4++) {
      float4 wv[4];
      #pragma unroll
      for (int j = 0; j < 4; j++)
        wv[j] = *(const float4*)&sW[(v0 + j)*68 + k4*4];
      #pragma unroll
      for (int kk = 0; kk < 4; kk++) {
        float4 x4 = *(const float4*)&sXT[(k4*4 + kk)*68 + tl0];
        #pragma unroll
        for (int j = 0; j < 4; j++) {
          float w = kk==0 ? wv[j].x : kk==1 ? wv[j].y : kk==2 ? wv[j].z : wv[j].w;
          a2[0][j] = fmaf(x4.x, w, a2[0][j]);
          a2[1][j] = fmaf(x4.y, w, a2[1][j]);
          a2[2][j] = fmaf(x4.z, w, a2[2][j]);
          a2[3][j] = fmaf(x4.w, w, a2[3][j]);
        }
      }
    }

    float* dst = (pass == 0) ? XM : Zb;
    #pragma unroll
    for (int ti = 0; ti < 4; ti++)
      *(float4*)&dst[(r*256 + t0 + tl0 + ti)*64 + v0] =
          make_float4(a2[ti][0], a2[ti][1], a2[ti][2], a2[ti][3]);
  }
}

// ---------------------------------------------------------------------------
// K2: conv+silu -> XC ; dbc = xc @ x_proj_w.T -> (dt | B | C) ; delta=softplus(...)
// grid 512 = 128 rows x 4 t-tiles(64), block 256
// ---------------------------------------------------------------------------
__global__ __launch_bounds__(256) void k2_conv_xproj(
    const float* __restrict__ XM, const float* __restrict__ convw,
    const float* __restrict__ convb, const float* __restrict__ xpw,
    const float* __restrict__ dtw, const float* __restrict__ dtb,
    float* __restrict__ XC, float* __restrict__ DELTA,
    float* __restrict__ BM, float* __restrict__ CM)
{
  __shared__ float sXM[65*64];    // [tt in -1..63][d]
  __shared__ float sXC[64*68];    // xc transposed [d][t], stride 68
  __shared__ float sW[64*68];     // staged x_proj_w tile
  __shared__ float sDT[64*5];     // dt[t][4], stride 5
  const int bid = blockIdx.x;
  const int r = bid >> 2, tb = bid & 3;
  const int t0 = tb * 64;
  const int tid = threadIdx.x;
  const int tg = tid & 15, vg = tid >> 4;
  const int tl0 = tg * 4, v0 = vg * 4;

  for (int e = tid; e < 65*64; e += 256) {
    int tt = e >> 6, d = e & 63;
    int tgl = t0 - 1 + tt;
    sXM[e] = (tgl < 0) ? 0.f : XM[(r*256 + tgl)*64 + d];
  }
  __syncthreads();

  for (int e = tid; e < 64*64; e += 256) {
    int t = e >> 6, d = e & 63;
    float c0 = convw[d*2], c1 = convw[d*2 + 1];
    float pre = fmaf(sXM[t*64 + d], c0, fmaf(sXM[(t+1)*64 + d], c1, convb[d]));
    float v = silu_f(pre);
    sXC[d*68 + t] = v;                       // transposed store
    XC[(r*256 + t0 + t)*64 + d] = v;         // coalesced global store
  }

  // dbc[t][j] = sum_d xc[d][t] * xpw[j][d],  j in 0..259 -> 5 passes of 64
  for (int pass = 0; pass < 5; pass++) {
    __syncthreads();   // sXC ready (pass0) / sW read-done
    for (int e = tid; e < 64*16; e += 256) {
      int row = e >> 4, c4 = e & 15;
      int grow = pass*64 + row;
      float4 w = (grow < 260) ? *(const float4*)&xpw[grow*64 + c4*4]
                              : make_float4(0.f, 0.f, 0.f, 0.f);
      *(float4*)&sW[row*68 + c4*4] = w;
    }
    __syncthreads();

    float acc[4][4];
    #pragma unroll
    for (int ti = 0; ti < 4; ti++)
      #pragma unroll
      for (int jj = 0; jj < 4; jj++) acc[ti][jj] = 0.f;

    for (int k4 = 0; k4 < 16; k4++) {
      float4 wv[4];
      #pragma unroll
      for (int jj = 0; jj < 4; jj++)
        wv[jj] = *(const float4*)&sW[(v0 + jj)*68 + k4*4];
      #pragma unroll
      for (int kk = 0; kk < 4; kk++) {
        float4 x4 = *(const float4*)&sXC[(k4*4 + kk)*68 + tl0];
        #pragma unroll
        for (int jj = 0; jj < 4; jj++) {
          float w = kk==0 ? wv[jj].x : kk==1 ? wv[jj].y : kk==2 ? wv[jj].z : wv[jj].w;
          acc[0][jj] = fmaf(x4.x, w, acc[0][jj]);
          acc[1][jj] = fmaf(x4.y, w, acc[1][jj]);
          acc[2][jj] = fmaf(x4.z, w, acc[2][jj]);
          acc[3][jj] = fmaf(x4.w, w, acc[3][jj]);
        }
      }
    }

    const int j0g = pass*64 + v0;   // multiple of 4; region bounds 4,132,260 are too
    if (j0g < 4) {
      #pragma unroll
      for (int ti = 0; ti < 4; ti++)
        #pragma unroll
        for (int jj = 0; jj < 4; jj++)
          sDT[(tl0 + ti)*5 + jj] = acc[ti][jj];
    } else if (j0g < 132) {
      #pragma unroll
      for (int ti = 0; ti < 4; ti++)
        *(float4*)&BM[(r*256 + t0 + tl0 + ti)*128 + (j0g - 4)] =
            make_float4(acc[ti][0], acc[ti][1], acc[ti][2], acc[ti][3]);
    } else if (j0g < 260) {
      #pragma unroll
      for (int ti = 0; ti < 4; ti++)
        *(float4*)&CM[(r*256 + t0 + tl0 + ti)*128 + (j0g - 132)] =
            make_float4(acc[ti][0], acc[ti][1], acc[ti][2], acc[ti][3]);
    }
  }
  __syncthreads();

  for (int e = tid; e < 64*64; e += 256) {
    int t = e >> 6, d = e & 63;
    float4 w4 = *(const float4*)&dtw[d*4];
    float x = dtb[d];
    x = fmaf(sDT[t*5 + 0], w4.x, x);
    x = fmaf(sDT[t*5 + 1], w4.y, x);
    x = fmaf(sDT[t*5 + 2], w4.z, x);
    x = fmaf(sDT[t*5 + 3], w4.w, x);
    DELTA[(r*256 + t0 + t)*64 + d] = softplus_f(x);
  }
}

// ---------------------------------------------------------------------------
// K3: selective scan (unchanged this round). grid 256 = 128 rows x 2 s-chunks(64).
// ---------------------------------------------------------------------------
__global__ __launch_bounds__(256) void k3_scan(
    const float* __restrict__ DELTA, const float* __restrict__ XC,
    const float* __restrict__ BM, const float* __restrict__ CM,
    const float* __restrict__ alog, float* __restrict__ YP)
{
  __shared__ float sD[8*64], sX[8*64], sB[8*64], sC[8*64];
  const int bid = blockIdx.x;
  const int r = bid & 127, sc = bid >> 7;
  const int tid = threadIdx.x;
  const int dg = tid >> 4, sg = tid & 15;
  const int d0 = dg * 4, s0 = sc*64 + sg*4;

  float a[4][4], h[4][4];
  #pragma unroll
  for (int i = 0; i < 4; i++)
    #pragma unroll
    for (int j = 0; j < 4; j++) {
      a[i][j] = -expf(alog[(d0 + i)*128 + s0 + j]);
      h[i][j] = 0.f;
    }

  for (int tb = 0; tb < 32; tb++) {
    for (int e = tid; e < 512; e += 256) {
      int tt = e >> 6, q = e & 63;
      int t = tb*8 + tt;
      sD[e] = DELTA[(r*256 + t)*64 + q];
      sX[e] = XC[(r*256 + t)*64 + q];
      sB[e] = BM[(r*256 + t)*128 + sc*64 + q];
      sC[e] = CM[(r*256 + t)*128 + sc*64 + q];
    }
    __syncthreads();

    #pragma unroll
    for (int tt = 0; tt < 8; tt++) {
      float4 dl4 = *(const float4*)&sD[tt*64 + d0];
      float4 xc4 = *(const float4*)&sX[tt*64 + d0];
      float4 B4  = *(const float4*)&sB[tt*64 + sg*4];
      float4 C4  = *(const float4*)&sC[tt*64 + sg*4];
      float dl[4] = {dl4.x, dl4.y, dl4.z, dl4.w};
      float xc[4] = {xc4.x, xc4.y, xc4.z, xc4.w};
      float Bv[4] = {B4.x, B4.y, B4.z, B4.w};
      float Cv[4] = {C4.x, C4.y, C4.z, C4.w};
      float y[4];
      #pragma unroll
      for (int i = 0; i < 4; i++) {
        float u = dl[i] * xc[i];
        float yp = 0.f;
        #pragma unroll
        for (int j = 0; j < 4; j++) {
          float dA = __expf(dl[i] * a[i][j]);
          h[i][j] = fmaf(dA, h[i][j], u * Bv[j]);
          yp = fmaf(h[i][j], Cv[j], yp);
        }
        y[i] = yp;
      }
      #pragma unroll
      for (int i = 0; i < 4; i++) {
        float yp = y[i];
        yp += __shfl_xor(yp, 1);
        yp += __shfl_xor(yp, 2);
        yp += __shfl_xor(yp, 4);
        yp += __shfl_xor(yp, 8);
        y[i] = yp;
      }
      if (sg == 0) {
        int t = tb*8 + tt;
        float4 v = make_float4(y[0], y[1], y[2], y[3]);
        *(float4*)&YP[((sc*128 + r)*256 + t)*64 + d0] = v;
      }
    }
    __syncthreads();
  }
}

// ---------------------------------------------------------------------------
// K4: y=yp0+yp1 ; y2=y+xc*D ; y3=y2*silu(z) ; u=silu(y3@opw.T) ;
//     v=u@wout.T+bout -> d_out (pre-LN) + per-block stats
// grid 512 = 128 rows x 4 t-tiles(64), block 256
// ---------------------------------------------------------------------------
__global__ __launch_bounds__(256) void k4_post(
    const float* __restrict__ YP, const float* __restrict__ XC,
    const float* __restrict__ Zb, const float* __restrict__ Dp,
    const float* __restrict__ opw, const float* __restrict__ wout,
    const float* __restrict__ bout, float* __restrict__ out,
    float* __restrict__ PSTAT)
{
  __shared__ float sY[64*68];   // y3 transposed [d][t]
  __shared__ float sU[64*68];   // u transposed [e][t]
  __shared__ float sW[64*68];
  __shared__ float sRs[256], sRq[256];
  const int bid = blockIdx.x;
  const int r = bid >> 2, tb = bid & 3;
  const int b = r >> 5, node = r & 31;
  const int t0 = tb * 64;
  const int tid = threadIdx.x;
  const int tg = tid & 15, vg = tid >> 4;
  const int tl0 = tg * 4, v0 = vg * 4;

  for (int e = tid; e < 64*64; e += 256) {
    int t = e >> 6, d = e & 63;
    int idx = (r*256 + t0 + t)*64 + d;
    float y = YP[idx] + YP[2097152 + idx];
    float y2 = fmaf(XC[idx], Dp[d], y);
    sY[d*68 + t] = y2 * silu_f(Zb[idx]);
  }

  // Phase A: u[t][e'] = silu( sum_d y3[d][t] * opw[e'][d] )
  __syncthreads();
  for (int e = tid; e < 64*16; e += 256) {
    int row = e >> 4, c4 = e & 15;
    *(float4*)&sW[row*68 + c4*4] = *(const float4*)&opw[row*64 + c4*4];
  }
  __syncthreads();

  {
    float acc[4][4];
    #pragma unroll
    for (int ti = 0; ti < 4; ti++)
      #pragma unroll
      for (int j = 0; j < 4; j++) acc[ti][j] = 0.f;
    for (int k4 = 0; k4 < 16; k4++) {
      float4 wv[4];
      #pragma unroll
      for (int j = 0; j < 4; j++)
        wv[j] = *(const float4*)&sW[(v0 + j)*68 + k4*4];
      #pragma unroll
      for (int kk = 0; kk < 4; kk++) {
        float4 x4 = *(const float4*)&sY[(k4*4 + kk)*68 + tl0];
        #pragma unroll
        for (int j = 0; j < 4; j++) {
          float w = kk==0 ? wv[j].x : kk==1 ? wv[j].y : kk==2 ? wv[j].z : wv[j].w;
          acc[0][j] = fmaf(x4.x, w, acc[0][j]);
          acc[1][j] = fmaf(x4.y, w, acc[1][j]);
          acc[2][j] = fmaf(x4.z, w, acc[2][j]);
          acc[3][j] = fmaf(x4.w, w, acc[3][j]);
        }
      }
    }
    #pragma unroll
    for (int j = 0; j < 4; j++)
      *(float4*)&sU[(v0 + j)*68 + tl0] =
          make_float4(silu_f(acc[0][j]), silu_f(acc[1][j]),
                      silu_f(acc[2][j]), silu_f(acc[3][j]));
  }

  // Phase B: v[t][o] = bout[o] + sum_e u[e][t] * wout[o][e]  (o: 2 passes of 64)
  float s = 0.f, q = 0.f;
  for (int pass = 0; pass < 2; pass++) {
    __syncthreads();   // sU visible (pass0) / sW read-done
    for (int e = tid; e < 64*16; e += 256) {
      int row = e >> 4, c4 = e & 15;
      *(float4*)&sW[row*68 + c4*4] = *(const float4*)&wout[(pass*64 + row)*64 + c4*4];
    }
    __syncthreads();

    float a2[4][4];
    #pragma unroll
    for (int ti = 0; ti < 4; ti++)
      #pragma unroll
      for (int j = 0; j < 4; j++) a2[ti][j] = bout[pass*64 + v0 + j];

    for (int k4 = 0; k4 < 16; k4++) {
      float4 wv[4];
      #pragma unroll
      for (int j = 0; j < 4; j++)
        wv[j] = *(const float4*)&sW[(v0 + j)*68 + k4*4];
      #pragma unroll
      for (int kk = 0; kk < 4; kk++) {
        float4 x4 = *(const float4*)&sU[(k4*4 + kk)*68 + tl0];
        #pragma unroll
        for (int j = 0; j < 4; j++) {
          float w = kk==0 ? wv[j].x : kk==1 ? wv[j].y : kk==2 ? wv[j].z : wv[j].w;
          a2[0][j] = fmaf(x4.x, w, a2[0][j]);
          a2[1][j] = fmaf(x4.y, w, a2[1][j]);
          a2[2][j] = fmaf(x4.z, w, a2[2][j]);
          a2[3][j] = fmaf(x4.w, w, a2[3][j]);
        }
      }
    }

    #pragma unroll
    for (int ti = 0; ti < 4; ti++)
      #pragma unroll
      for (int j = 0; j < 4; j++) {
        float v = a2[ti][j];
        s += v;
        q = fmaf(v, v, q);
      }
    #pragma unroll
    for (int j = 0; j < 4; j++) {
      int o = pass*64 + v0 + j;
      *(float4*)&out[((b*128 + o)*32 + node)*256 + t0 + tl0] =
          make_float4(a2[0][j], a2[1][j], a2[2][j], a2[3][j]);
    }
  }

  sRs[tid] = s; sRq[tid] = q;
  __syncthreads();
  for (int st = 128; st > 0; st >>= 1) {
    if (tid < st) { sRs[tid] += sRs[tid + st]; sRq[tid] += sRq[tid + st]; }
    __syncthreads();
  }
  if (tid == 0) { PSTAT[bid*2] = sRs[0]; PSTAT[bid*2 + 1] = sRq[0]; }
}

// ---------------------------------------------------------------------------
// K5: LayerNorm in place on d_out (unchanged). grid 1024, block 256
// ---------------------------------------------------------------------------
__global__ __launch_bounds__(256) void k5_ln(
    const float* __restrict__ PSTAT, const float* __restrict__ lnw,
    const float* __restrict__ lnb, float* __restrict__ out)
{
  __shared__ float sLW[32*129], sLB[32*129];
  const int bid = blockIdx.x;
  const int r = bid >> 3, tb = bid & 7;
  const int b = r >> 5, node = r & 31;
  const int t0 = tb * 32;
  const int tid = threadIdx.x;

  float s = 0.f, q = 0.f;
  #pragma unroll
  for (int p = 0; p < 4; p++) {
    s += PSTAT[(r*4 + p)*2];
    q += PSTAT[(r*4 + p)*2 + 1];
  }
  const float mu = s * (1.f / 32768.f);
  const float var = q * (1.f / 32768.f) - mu * mu;
  const float rstd = rsqrtf(var + 1e-5f);

  for (int e = tid; e < 32*128; e += 256) {
    int t = e >> 7, o = e & 127;
    sLW[t*129 + o] = lnw[(t0 + t)*128 + o];
    sLB[t*129 + o] = lnb[(t0 + t)*128 + o];
  }
  __syncthreads();

  for (int n = 0; n < 16; n++) {
    int t = tid & 31;
    int o = (tid >> 5) + n*8;
    int idx = ((b*128 + o)*32 + node)*256 + t0 + t;
    float v = out[idx];
    out[idx] = fmaf((v - mu) * rstd, sLW[t*129 + o], sLB[t*129 + o]);
  }
}

// ---------------------------------------------------------------------------
extern "C" void kernel_launch(void* const* d_in, const int* in_sizes, int n_in,
                              void* d_out, int out_size, void* d_ws, size_t ws_size,
                              hipStream_t stream)
{
  (void)in_sizes; (void)n_in; (void)out_size; (void)ws_size;
  const float* inp   = (const float*)d_in[0];
  const float* w_in  = (const float*)d_in[1];
  const float* b_in  = (const float*)d_in[2];
  const float* ipw   = (const float*)d_in[3];
  const float* convw = (const float*)d_in[4];
  const float* convb = (const float*)d_in[5];
  const float* xpw   = (const float*)d_in[6];
  const float* dtw   = (const float*)d_in[7];
  const float* dtb   = (const float*)d_in[8];
  const float* alog  = (const float*)d_in[9];
  const float* Dp    = (const float*)d_in[10];
  const float* opw   = (const float*)d_in[11];
  const float* wout  = (const float*)d_in[12];
  const float* bout  = (const float*)d_in[13];
  const float* lnw   = (const float*)d_in[14];
  const float* lnb   = (const float*)d_in[15];

  float* ws = (float*)d_ws;
  float* XM    = ws + 0;
  float* Zb    = ws + 2097152;
  float* XC    = ws + 4194304;
  float* DELTA = ws + 6291456;
  float* BM    = ws + 8388608;
  float* CM    = ws + 12582912;
  float* YP    = ws + 16777216;   // 2 x 128 x 256 x 64
  float* PSTAT = ws + 20971520;   // 512 x 2
  float* out   = (float*)d_out;

  k1_proj<<<dim3(512), dim3(256), 0, stream>>>(inp, w_in, b_in, ipw, XM, Zb);
  k2_conv_xproj<<<dim3(512), dim3(256), 0, stream>>>(XM, convw, convb, xpw, dtw, dtb,
                                                     XC, DELTA, BM, CM);
  k3_scan<<<dim3(256), dim3(256), 0, stream>>>(DELTA, XC, BM, CM, alog, YP);
  k4_post<<<dim3(512), dim3(256), 0, stream>>>(YP, XC, Zb, Dp, opw, wout, bout, out, PSTAT);
  k5_ln<<<dim3(1024), dim3(256), 0, stream>>>(PSTAT, lnw, lnb, out);
}

// Round 6
// 185.719 us; speedup vs baseline: 2.1442x; 1.2206x over previous
//
#include <hip/hip_runtime.h>
#include <math.h>

// Problem dims
// B=4, N_IN=128, NODE=32, L=256, N_HID=D_IN=64, D_STATE=128, DT_RANK=4, N_OUT=128
// R = B*NODE = 128 rows, each row independent; L sequential only in the scan (k3).
//
// R4 change: k3 rewritten. Was grid 256 (1 block/CU, occupancy 11%, VALUBusy 33%,
// 138us): scan latency-bound with 1 wave/SIMD and exposed staging latency.
// Now grid 1024 (rows x 2 s-chunks x 4 d-chunks) = 4 blocks/CU, plus
// register-double-buffered LDS staging (next tile's global loads issued before
// computing current tile). k1/k2/k4/k5 unchanged from R3.

__device__ __forceinline__ float silu_f(float v) { return v / (1.f + __expf(-v)); }
__device__ __forceinline__ float softplus_f(float v) { return v > 20.f ? v : log1pf(__expf(v)); }

// ---------------------------------------------------------------------------
// K1: X = in @ w_in.T + b_in ; XZ = X @ in_proj_w.T -> XM (first 64), Z (last 64)
// grid 512 = 128 rows x 4 t-tiles(64), block 256
// ---------------------------------------------------------------------------
__global__ __launch_bounds__(256) void k1_proj(
    const float* __restrict__ inp, const float* __restrict__ w_in,
    const float* __restrict__ b_in, const float* __restrict__ ipw,
    float* __restrict__ XM, float* __restrict__ Zb)
{
  __shared__ float sIN[128*64];   // [i=128][t=64]
  __shared__ float sW[64*68];     // staged weight tile [row][k], stride 68
  __shared__ float sXT[64*68];    // X transposed [h][t], stride 68
  const int bid = blockIdx.x;
  const int r = bid >> 2, tb = bid & 3;
  const int b = r >> 5, node = r & 31;
  const int t0 = tb * 64;
  const int tid = threadIdx.x;
  const int tg = tid & 15, vg = tid >> 4;
  const int tl0 = tg * 4, v0 = vg * 4;

  for (int e = tid; e < 128*64; e += 256) {
    int i = e >> 6, t = e & 63;
    sIN[e] = inp[((b*128 + i)*32 + node)*256 + t0 + t];
  }

  // Phase A: X[t][h] = b_in[h] + sum_i in[i][t] * w_in[h][i]   (K=128, 2 chunks)
  float acc[4][4];
  #pragma unroll
  for (int ti = 0; ti < 4; ti++)
    #pragma unroll
    for (int j = 0; j < 4; j++) acc[ti][j] = b_in[v0 + j];

  for (int kc = 0; kc < 2; kc++) {
    __syncthreads();   // sIN ready (kc=0) / sW read-done (kc=1)
    for (int e = tid; e < 64*16; e += 256) {
      int row = e >> 4, c4 = e & 15;
      *(float4*)&sW[row*68 + c4*4] = *(const float4*)&w_in[row*128 + kc*64 + c4*4];
    }
    __syncthreads();
    for (int k4 = 0; k4 < 16; k4++) {
      float4 wv[4];
      #pragma unroll
      for (int j = 0; j < 4; j++)
        wv[j] = *(const float4*)&sW[(v0 + j)*68 + k4*4];
      #pragma unroll
      for (int kk = 0; kk < 4; kk++) {
        float4 x4 = *(const float4*)&sIN[(kc*64 + k4*4 + kk)*64 + tl0];
        #pragma unroll
        for (int j = 0; j < 4; j++) {
          float w = kk==0 ? wv[j].x : kk==1 ? wv[j].y : kk==2 ? wv[j].z : wv[j].w;
          acc[0][j] = fmaf(x4.x, w, acc[0][j]);
          acc[1][j] = fmaf(x4.y, w, acc[1][j]);
          acc[2][j] = fmaf(x4.z, w, acc[2][j]);
          acc[3][j] = fmaf(x4.w, w, acc[3][j]);
        }
      }
    }
  }
  // stash X^T into sXT[h][t]
  #pragma unroll
  for (int j = 0; j < 4; j++)
    *(float4*)&sXT[(v0 + j)*68 + tl0] =
        make_float4(acc[0][j], acc[1][j], acc[2][j], acc[3][j]);

  // Phase B: XZ[t][c] = sum_h X[h][t] * ipw[c][h]   (c: 2 passes of 64)
  for (int pass = 0; pass < 2; pass++) {
    __syncthreads();   // sXT visible (pass0) / sW read-done
    for (int e = tid; e < 64*16; e += 256) {
      int row = e >> 4, c4 = e & 15;
      *(float4*)&sW[row*68 + c4*4] = *(const float4*)&ipw[(pass*64 + row)*64 + c4*4];
    }
    __syncthreads();

    float a2[4][4];
    #pragma unroll
    for (int ti = 0; ti < 4; ti++)
      #pragma unroll
      for (int j = 0; j < 4; j++) a2[ti][j] = 0.f;

    for (int k4 = 0; k4 < 16; k4++) {
      float4 wv[4];
      #pragma unroll
      for (int j = 0; j < 4; j++)
        wv[j] = *(const float4*)&sW[(v0 + j)*68 + k4*4];
      #pragma unroll
      for (int kk = 0; kk < 4; kk++) {
        float4 x4 = *(const float4*)&sXT[(k4*4 + kk)*68 + tl0];
        #pragma unroll
        for (int j = 0; j < 4; j++) {
          float w = kk==0 ? wv[j].x : kk==1 ? wv[j].y : kk==2 ? wv[j].z : wv[j].w;
          a2[0][j] = fmaf(x4.x, w, a2[0][j]);
          a2[1][j] = fmaf(x4.y, w, a2[1][j]);
          a2[2][j] = fmaf(x4.z, w, a2[2][j]);
          a2[3][j] = fmaf(x4.w, w, a2[3][j]);
        }
      }
    }

    float* dst = (pass == 0) ? XM : Zb;
    #pragma unroll
    for (int ti = 0; ti < 4; ti++)
      *(float4*)&dst[(r*256 + t0 + tl0 + ti)*64 + v0] =
          make_float4(a2[ti][0], a2[ti][1], a2[ti][2], a2[ti][3]);
  }
}

// ---------------------------------------------------------------------------
// K2: conv+silu -> XC ; dbc = xc @ x_proj_w.T -> (dt | B | C) ; delta=softplus(...)
// grid 512 = 128 rows x 4 t-tiles(64), block 256
// ---------------------------------------------------------------------------
__global__ __launch_bounds__(256) void k2_conv_xproj(
    const float* __restrict__ XM, const float* __restrict__ convw,
    const float* __restrict__ convb, const float* __restrict__ xpw,
    const float* __restrict__ dtw, const float* __restrict__ dtb,
    float* __restrict__ XC, float* __restrict__ DELTA,
    float* __restrict__ BM, float* __restrict__ CM)
{
  __shared__ float sXM[65*64];    // [tt in -1..63][d]
  __shared__ float sXC[64*68];    // xc transposed [d][t], stride 68
  __shared__ float sW[64*68];     // staged x_proj_w tile
  __shared__ float sDT[64*5];     // dt[t][4], stride 5
  const int bid = blockIdx.x;
  const int r = bid >> 2, tb = bid & 3;
  const int t0 = tb * 64;
  const int tid = threadIdx.x;
  const int tg = tid & 15, vg = tid >> 4;
  const int tl0 = tg * 4, v0 = vg * 4;

  for (int e = tid; e < 65*64; e += 256) {
    int tt = e >> 6, d = e & 63;
    int tgl = t0 - 1 + tt;
    sXM[e] = (tgl < 0) ? 0.f : XM[(r*256 + tgl)*64 + d];
  }
  __syncthreads();

  for (int e = tid; e < 64*64; e += 256) {
    int t = e >> 6, d = e & 63;
    float c0 = convw[d*2], c1 = convw[d*2 + 1];
    float pre = fmaf(sXM[t*64 + d], c0, fmaf(sXM[(t+1)*64 + d], c1, convb[d]));
    float v = silu_f(pre);
    sXC[d*68 + t] = v;                       // transposed store
    XC[(r*256 + t0 + t)*64 + d] = v;         // coalesced global store
  }

  // dbc[t][j] = sum_d xc[d][t] * xpw[j][d],  j in 0..259 -> 5 passes of 64
  for (int pass = 0; pass < 5; pass++) {
    __syncthreads();   // sXC ready (pass0) / sW read-done
    for (int e = tid; e < 64*16; e += 256) {
      int row = e >> 4, c4 = e & 15;
      int grow = pass*64 + row;
      float4 w = (grow < 260) ? *(const float4*)&xpw[grow*64 + c4*4]
                              : make_float4(0.f, 0.f, 0.f, 0.f);
      *(float4*)&sW[row*68 + c4*4] = w;
    }
    __syncthreads();

    float acc[4][4];
    #pragma unroll
    for (int ti = 0; ti < 4; ti++)
      #pragma unroll
      for (int jj = 0; jj < 4; jj++) acc[ti][jj] = 0.f;

    for (int k4 = 0; k4 < 16; k4++) {
      float4 wv[4];
      #pragma unroll
      for (int jj = 0; jj < 4; jj++)
        wv[jj] = *(const float4*)&sW[(v0 + jj)*68 + k4*4];
      #pragma unroll
      for (int kk = 0; kk < 4; kk++) {
        float4 x4 = *(const float4*)&sXC[(k4*4 + kk)*68 + tl0];
        #pragma unroll
        for (int jj = 0; jj < 4; jj++) {
          float w = kk==0 ? wv[jj].x : kk==1 ? wv[jj].y : kk==2 ? wv[jj].z : wv[jj].w;
          acc[0][jj] = fmaf(x4.x, w, acc[0][jj]);
          acc[1][jj] = fmaf(x4.y, w, acc[1][jj]);
          acc[2][jj] = fmaf(x4.z, w, acc[2][jj]);
          acc[3][jj] = fmaf(x4.w, w, acc[3][jj]);
        }
      }
    }

    const int j0g = pass*64 + v0;   // multiple of 4; region bounds 4,132,260 are too
    if (j0g < 4) {
      #pragma unroll
      for (int ti = 0; ti < 4; ti++)
        #pragma unroll
        for (int jj = 0; jj < 4; jj++)
          sDT[(tl0 + ti)*5 + jj] = acc[ti][jj];
    } else if (j0g < 132) {
      #pragma unroll
      for (int ti = 0; ti < 4; ti++)
        *(float4*)&BM[(r*256 + t0 + tl0 + ti)*128 + (j0g - 4)] =
            make_float4(acc[ti][0], acc[ti][1], acc[ti][2], acc[ti][3]);
    } else if (j0g < 260) {
      #pragma unroll
      for (int ti = 0; ti < 4; ti++)
        *(float4*)&CM[(r*256 + t0 + tl0 + ti)*128 + (j0g - 132)] =
            make_float4(acc[ti][0], acc[ti][1], acc[ti][2], acc[ti][3]);
    }
  }
  __syncthreads();

  for (int e = tid; e < 64*64; e += 256) {
    int t = e >> 6, d = e & 63;
    float4 w4 = *(const float4*)&dtw[d*4];
    float x = dtb[d];
    x = fmaf(sDT[t*5 + 0], w4.x, x);
    x = fmaf(sDT[t*5 + 1], w4.y, x);
    x = fmaf(sDT[t*5 + 2], w4.z, x);
    x = fmaf(sDT[t*5 + 3], w4.w, x);
    DELTA[(r*256 + t0 + t)*64 + d] = softplus_f(x);
  }
}

// ---------------------------------------------------------------------------
// K3: selective scan, R4 rewrite.
// grid 1024: bid -> r (128 rows) x sc (2 s-chunks of 64) x dc (4 d-chunks of 16).
// block 256: dg = tid>>4 (16 d's), sg = tid&15 (16 s-groups of 4 states).
// Thread owns 1 d x 4 s states in registers for all 256 timesteps.
// Register-double-buffered LDS staging: next tile's global loads issued
// before computing the current tile.
// Writes YP[sc][r][t][d] partials (2 partials, same layout as R3).
// ---------------------------------------------------------------------------
__global__ __launch_bounds__(256) void k3_scan(
    const float* __restrict__ DELTA, const float* __restrict__ XC,
    const float* __restrict__ BM, const float* __restrict__ CM,
    const float* __restrict__ alog, float* __restrict__ YP)
{
  // LDS layout (floats): [0,512) sB[8][64] | [512,1024) sC[8][64]
  //                      [1024,1152) sD[8][16] | [1152,1280) sX[8][16]
  __shared__ float sT[1280];
  const int bid = blockIdx.x;
  const int r = bid & 127;
  const int rest = bid >> 7;
  const int sc = rest & 1;        // s-chunk: 64 states
  const int dc = rest >> 1;       // d-chunk: 16 channels
  const int tid = threadIdx.x;
  const int dg = tid >> 4;        // d within chunk
  const int sg = tid & 15;        // s-group (4 states each)
  const int sl0 = sg * 4;
  const int d = dc*16 + dg;
  const int sbase = sc*64 + sl0;

  float a[4], h[4];
  #pragma unroll
  for (int j = 0; j < 4; j++) {
    a[j] = -expf(alog[d*128 + sbase + j]);
    h[j] = 0.f;
  }

  const float* baseB = BM + r*256*128 + sc*64;
  const float* baseC = CM + r*256*128 + sc*64;
  const float* baseD = DELTA + r*256*64 + dc*16;
  const float* baseX = XC + r*256*64 + dc*16;

  float pre0, pre1, pre2, pre3, pre4;
  const int ttB = tid >> 6, qB = tid & 63;       // for sB/sC rows
  const int ttD = (tid & 127) >> 4, qD = tid & 15; // for sD/sX

  // ---- stage tile tb into regs
  #define K3_LOAD(tb_) do { \
    int t0_ = (tb_)*8; \
    pre0 = baseB[(t0_ + ttB)*128 + qB]; \
    pre1 = baseB[(t0_ + 4 + ttB)*128 + qB]; \
    pre2 = baseC[(t0_ + ttB)*128 + qB]; \
    pre3 = baseC[(t0_ + 4 + ttB)*128 + qB]; \
    pre4 = (tid < 128) ? baseD[(t0_ + ttD)*64 + qD] : baseX[(t0_ + ttD)*64 + qD]; \
  } while (0)

  #define K3_STORE() do { \
    sT[ttB*64 + qB] = pre0; \
    sT[(4 + ttB)*64 + qB] = pre1; \
    sT[512 + ttB*64 + qB] = pre2; \
    sT[512 + (4 + ttB)*64 + qB] = pre3; \
    sT[((tid < 128) ? 1024 : 1152) + ttD*16 + qD] = pre4; \
  } while (0)

  K3_LOAD(0);
  K3_STORE();
  __syncthreads();

  for (int tb = 0; tb < 32; tb++) {
    if (tb < 31) K3_LOAD(tb + 1);   // issue next tile's global loads early

    #pragma unroll
    for (int tt = 0; tt < 8; tt++) {
      float dl = sT[1024 + tt*16 + dg];
      float xv = sT[1152 + tt*16 + dg];
      float u  = dl * xv;
      float4 Bv = *(const float4*)&sT[tt*64 + sl0];
      float4 Cv = *(const float4*)&sT[512 + tt*64 + sl0];
      float y = 0.f;
      {
        float dA0 = __expf(dl * a[0]);
        h[0] = fmaf(dA0, h[0], u * Bv.x);
        y = fmaf(h[0], Cv.x, y);
        float dA1 = __expf(dl * a[1]);
        h[1] = fmaf(dA1, h[1], u * Bv.y);
        y = fmaf(h[1], Cv.y, y);
        float dA2 = __expf(dl * a[2]);
        h[2] = fmaf(dA2, h[2], u * Bv.z);
        y = fmaf(h[2], Cv.z, y);
        float dA3 = __expf(dl * a[3]);
        h[3] = fmaf(dA3, h[3], u * Bv.w);
        y = fmaf(h[3], Cv.w, y);
      }
      y += __shfl_xor(y, 1);
      y += __shfl_xor(y, 2);
      y += __shfl_xor(y, 4);
      y += __shfl_xor(y, 8);
      if (sg == 0)
        YP[((sc*128 + r)*256 + tb*8 + tt)*64 + d] = y;
    }

    __syncthreads();                 // all lanes done reading sT
    if (tb < 31) {
      K3_STORE();                    // overwrite with next tile
      __syncthreads();               // stores visible
    }
  }
  #undef K3_LOAD
  #undef K3_STORE
}

// ---------------------------------------------------------------------------
// K4: y=yp0+yp1 ; y2=y+xc*D ; y3=y2*silu(z) ; u=silu(y3@opw.T) ;
//     v=u@wout.T+bout -> d_out (pre-LN) + per-block stats
// grid 512 = 128 rows x 4 t-tiles(64), block 256
// ---------------------------------------------------------------------------
__global__ __launch_bounds__(256) void k4_post(
    const float* __restrict__ YP, const float* __restrict__ XC,
    const float* __restrict__ Zb, const float* __restrict__ Dp,
    const float* __restrict__ opw, const float* __restrict__ wout,
    const float* __restrict__ bout, float* __restrict__ out,
    float* __restrict__ PSTAT)
{
  __shared__ float sY[64*68];   // y3 transposed [d][t]
  __shared__ float sU[64*68];   // u transposed [e][t]
  __shared__ float sW[64*68];
  __shared__ float sRs[256], sRq[256];
  const int bid = blockIdx.x;
  const int r = bid >> 2, tb = bid & 3;
  const int b = r >> 5, node = r & 31;
  const int t0 = tb * 64;
  const int tid = threadIdx.x;
  const int tg = tid & 15, vg = tid >> 4;
  const int tl0 = tg * 4, v0 = vg * 4;

  for (int e = tid; e < 64*64; e += 256) {
    int t = e >> 6, d = e & 63;
    int idx = (r*256 + t0 + t)*64 + d;
    float y = YP[idx] + YP[2097152 + idx];
    float y2 = fmaf(XC[idx], Dp[d], y);
    sY[d*68 + t] = y2 * silu_f(Zb[idx]);
  }

  // Phase A: u[t][e'] = silu( sum_d y3[d][t] * opw[e'][d] )
  __syncthreads();
  for (int e = tid; e < 64*16; e += 256) {
    int row = e >> 4, c4 = e & 15;
    *(float4*)&sW[row*68 + c4*4] = *(const float4*)&opw[row*64 + c4*4];
  }
  __syncthreads();

  {
    float acc[4][4];
    #pragma unroll
    for (int ti = 0; ti < 4; ti++)
      #pragma unroll
      for (int j = 0; j < 4; j++) acc[ti][j] = 0.f;
    for (int k4 = 0; k4 < 16; k4++) {
      float4 wv[4];
      #pragma unroll
      for (int j = 0; j < 4; j++)
        wv[j] = *(const float4*)&sW[(v0 + j)*68 + k4*4];
      #pragma unroll
      for (int kk = 0; kk < 4; kk++) {
        float4 x4 = *(const float4*)&sY[(k4*4 + kk)*68 + tl0];
        #pragma unroll
        for (int j = 0; j < 4; j++) {
          float w = kk==0 ? wv[j].x : kk==1 ? wv[j].y : kk==2 ? wv[j].z : wv[j].w;
          acc[0][j] = fmaf(x4.x, w, acc[0][j]);
          acc[1][j] = fmaf(x4.y, w, acc[1][j]);
          acc[2][j] = fmaf(x4.z, w, acc[2][j]);
          acc[3][j] = fmaf(x4.w, w, acc[3][j]);
        }
      }
    }
    #pragma unroll
    for (int j = 0; j < 4; j++)
      *(float4*)&sU[(v0 + j)*68 + tl0] =
          make_float4(silu_f(acc[0][j]), silu_f(acc[1][j]),
                      silu_f(acc[2][j]), silu_f(acc[3][j]));
  }

  // Phase B: v[t][o] = bout[o] + sum_e u[e][t] * wout[o][e]  (o: 2 passes of 64)
  float s = 0.f, q = 0.f;
  for (int pass = 0; pass < 2; pass++) {
    __syncthreads();   // sU visible (pass0) / sW read-done
    for (int e = tid; e < 64*16; e += 256) {
      int row = e >> 4, c4 = e & 15;
      *(float4*)&sW[row*68 + c4*4] = *(const float4*)&wout[(pass*64 + row)*64 + c4*4];
    }
    __syncthreads();

    float a2[4][4];
    #pragma unroll
    for (int ti = 0; ti < 4; ti++)
      #pragma unroll
      for (int j = 0; j < 4; j++) a2[ti][j] = bout[pass*64 + v0 + j];

    for (int k4 = 0; k4 < 16; k4++) {
      float4 wv[4];
      #pragma unroll
      for (int j = 0; j < 4; j++)
        wv[j] = *(const float4*)&sW[(v0 + j)*68 + k4*4];
      #pragma unroll
      for (int kk = 0; kk < 4; kk++) {
        float4 x4 = *(const float4*)&sU[(k4*4 + kk)*68 + tl0];
        #pragma unroll
        for (int j = 0; j < 4; j++) {
          float w = kk==0 ? wv[j].x : kk==1 ? wv[j].y : kk==2 ? wv[j].z : wv[j].w;
          a2[0][j] = fmaf(x4.x, w, a2[0][j]);
          a2[1][j] = fmaf(x4.y, w, a2[1][j]);
          a2[2][j] = fmaf(x4.z, w, a2[2][j]);
          a2[3][j] = fmaf(x4.w, w, a2[3][j]);
        }
      }
    }

    #pragma unroll
    for (int ti = 0; ti < 4; ti++)
      #pragma unroll
      for (int j = 0; j < 4; j++) {
        float v = a2[ti][j];
        s += v;
        q = fmaf(v, v, q);
      }
    #pragma unroll
    for (int j = 0; j < 4; j++) {
      int o = pass*64 + v0 + j;
      *(float4*)&out[((b*128 + o)*32 + node)*256 + t0 + tl0] =
          make_float4(a2[0][j], a2[1][j], a2[2][j], a2[3][j]);
    }
  }

  sRs[tid] = s; sRq[tid] = q;
  __syncthreads();
  for (int st = 128; st > 0; st >>= 1) {
    if (tid < st) { sRs[tid] += sRs[tid + st]; sRq[tid] += sRq[tid + st]; }
    __syncthreads();
  }
  if (tid == 0) { PSTAT[bid*2] = sRs[0]; PSTAT[bid*2 + 1] = sRq[0]; }
}

// ---------------------------------------------------------------------------
// K5: LayerNorm in place on d_out (unchanged). grid 1024, block 256
// ---------------------------------------------------------------------------
__global__ __launch_bounds__(256) void k5_ln(
    const float* __restrict__ PSTAT, const float* __restrict__ lnw,
    const float* __restrict__ lnb, float* __restrict__ out)
{
  __shared__ float sLW[32*129], sLB[32*129];
  const int bid = blockIdx.x;
  const int r = bid >> 3, tb = bid & 7;
  const int b = r >> 5, node = r & 31;
  const int t0 = tb * 32;
  const int tid = threadIdx.x;

  float s = 0.f, q = 0.f;
  #pragma unroll
  for (int p = 0; p < 4; p++) {
    s += PSTAT[(r*4 + p)*2];
    q += PSTAT[(r*4 + p)*2 + 1];
  }
  const float mu = s * (1.f / 32768.f);
  const float var = q * (1.f / 32768.f) - mu * mu;
  const float rstd = rsqrtf(var + 1e-5f);

  for (int e = tid; e < 32*128; e += 256) {
    int t = e >> 7, o = e & 127;
    sLW[t*129 + o] = lnw[(t0 + t)*128 + o];
    sLB[t*129 + o] = lnb[(t0 + t)*128 + o];
  }
  __syncthreads();

  for (int n = 0; n < 16; n++) {
    int t = tid & 31;
    int o = (tid >> 5) + n*8;
    int idx = ((b*128 + o)*32 + node)*256 + t0 + t;
    float v = out[idx];
    out[idx] = fmaf((v - mu) * rstd, sLW[t*129 + o], sLB[t*129 + o]);
  }
}

// ---------------------------------------------------------------------------
extern "C" void kernel_launch(void* const* d_in, const int* in_sizes, int n_in,
                              void* d_out, int out_size, void* d_ws, size_t ws_size,
                              hipStream_t stream)
{
  (void)in_sizes; (void)n_in; (void)out_size; (void)ws_size;
  const float* inp   = (const float*)d_in[0];
  const float* w_in  = (const float*)d_in[1];
  const float* b_in  = (const float*)d_in[2];
  const float* ipw   = (const float*)d_in[3];
  const float* convw = (const float*)d_in[4];
  const float* convb = (const float*)d_in[5];
  const float* xpw   = (const float*)d_in[6];
  const float* dtw   = (const float*)d_in[7];
  const float* dtb   = (const float*)d_in[8];
  const float* alog  = (const float*)d_in[9];
  const float* Dp    = (const float*)d_in[10];
  const float* opw   = (const float*)d_in[11];
  const float* wout  = (const float*)d_in[12];
  const float* bout  = (const float*)d_in[13];
  const float* lnw   = (const float*)d_in[14];
  const float* lnb   = (const float*)d_in[15];

  float* ws = (float*)d_ws;
  float* XM    = ws + 0;
  float* Zb    = ws + 2097152;
  float* XC    = ws + 4194304;
  float* DELTA = ws + 6291456;
  float* BM    = ws + 8388608;
  float* CM    = ws + 12582912;
  float* YP    = ws + 16777216;   // 2 x 128 x 256 x 64
  float* PSTAT = ws + 20971520;   // 512 x 2
  float* out   = (float*)d_out;

  k1_proj<<<dim3(512), dim3(256), 0, stream>>>(inp, w_in, b_in, ipw, XM, Zb);
  k2_conv_xproj<<<dim3(512), dim3(256), 0, stream>>>(XM, convw, convb, xpw, dtw, dtb,
                                                     XC, DELTA, BM, CM);
  k3_scan<<<dim3(1024), dim3(256), 0, stream>>>(DELTA, XC, BM, CM, alog, YP);
  k4_post<<<dim3(512), dim3(256), 0, stream>>>(YP, XC, Zb, Dp, opw, wout, bout, out, PSTAT);
  k5_ln<<<dim3(1024), dim3(256), 0, stream>>>(PSTAT, lnw, lnb, out);
}